// Round 1
// baseline (235.937 us; speedup 1.0000x reference)
//
#include <hip/hip_runtime.h>
#include <hip/hip_bf16.h>
#include <stdint.h>

typedef __bf16 bf16;
typedef __attribute__((ext_vector_type(8))) __bf16 bf16x8;
typedef __attribute__((ext_vector_type(4))) float f32x4;

#define L2E 1.4426950408889634f

__device__ __forceinline__ f32x4 mfma16(bf16x8 a, bf16x8 b, f32x4 c) {
  return __builtin_amdgcn_mfma_f32_16x16x32_bf16(a, b, c, 0, 0, 0);
}

__device__ __forceinline__ void gload16(void* lds, const void* g) {
  __builtin_amdgcn_global_load_lds(
      (const __attribute__((address_space(1))) uint32_t*)g,
      (__attribute__((address_space(3))) uint32_t*)lds, 16, 0, 0);
}

// ---------------- prep: fp32 -> bf16 ----------------
__global__ __launch_bounds__(256) void prep_cast(
    const float* __restrict__ x, const float* __restrict__ wq,
    const float* __restrict__ wk, const float* __restrict__ wv,
    const float* __restrict__ wo, bf16* __restrict__ xb,
    bf16* __restrict__ wqb, bf16* __restrict__ wkb, bf16* __restrict__ wvb,
    bf16* __restrict__ wob) {
  int i = blockIdx.x * 256 + threadIdx.x;  // unit of 4 floats
  const int NX = 4096 * 1024 / 4;
  const int NW = 1024 * 1024 / 4;
  const float* src; bf16* dst; int off;
  if (i < NX)               { src = x;  dst = xb;  off = i; }
  else if (i < NX + NW)     { src = wq; dst = wqb; off = i - NX; }
  else if (i < NX + 2 * NW) { src = wk; dst = wkb; off = i - (NX + NW); }
  else if (i < NX + 3 * NW) { src = wv; dst = wvb; off = i - (NX + 2 * NW); }
  else                      { src = wo; dst = wob; off = i - (NX + 3 * NW); }
  float4 v = ((const float4*)src)[off];
  union { bf16 h[4]; uint2 u; } o;
  o.h[0] = (bf16)v.x; o.h[1] = (bf16)v.y; o.h[2] = (bf16)v.z; o.h[3] = (bf16)v.w;
  ((uint2*)dst)[off] = o.u;
}

// ---------------- RoPE tables: [2048][32] fp32 ----------------
__global__ __launch_bounds__(256) void rope_tab(float* __restrict__ ct,
                                                float* __restrict__ st) {
  int i = blockIdx.x * 256 + threadIdx.x;  // 65536
  int t = i >> 5, d = i & 31;
  float inv = powf(10000.f, -(float)d * (1.f / 32.f));
  float a = (float)t * inv;
  ct[i] = cosf(a);
  st[i] = sinf(a);
}

// ---------------- shared GEMM mainloop: C = A[4096x1024] * W^T[1024x1024] tile
// 128x128 tile, BK=32, 4 waves 2x2, double-buffered LDS, swizzled (rule #21)
__device__ __forceinline__ void gemm_mainloop(const bf16* __restrict__ A,
                                              const bf16* __restrict__ W,
                                              int m0, int n0,
                                              bf16 (*As)[4096], bf16 (*Bs)[4096],
                                              f32x4 acc[4][4]) {
  const int tid = threadIdx.x;
  const int lane = tid & 63, wave = tid >> 6;
  const int wr = (wave >> 1) * 64, wc = (wave & 1) * 64;
  const int lr = lane & 15, lh = lane >> 4;

  auto stage = [&](bf16* dA, bf16* dB, int kt) {
    int k0 = kt * 32;
#pragma unroll
    for (int p = 0; p < 2; p++) {
      int u = p * 256 + tid; int row = u >> 2; int kg = (u & 3) ^ (row & 3);
      gload16(dA + (size_t)u * 8, A + (size_t)(m0 + row) * 1024 + k0 + kg * 8);
    }
#pragma unroll
    for (int p = 0; p < 2; p++) {
      int u = p * 256 + tid; int row = u >> 2; int kg = (u & 3) ^ (row & 3);
      gload16(dB + (size_t)u * 8, W + (size_t)(n0 + row) * 1024 + k0 + kg * 8);
    }
  };

  stage(As[0], Bs[0], 0);
  int cur = 0;
  for (int kt = 0; kt < 32; ++kt) {
    __syncthreads();
    const bf16* cA = As[cur]; const bf16* cB = Bs[cur];
    bf16x8 af[4], bfr[4];
#pragma unroll
    for (int i = 0; i < 4; i++) {
      int row = wr + i * 16 + lr; int un = row * 4 + (lh ^ (row & 3));
      af[i] = *(const bf16x8*)(cA + (size_t)un * 8);
    }
#pragma unroll
    for (int j = 0; j < 4; j++) {
      int row = wc + j * 16 + lr; int un = row * 4 + (lh ^ (row & 3));
      bfr[j] = *(const bf16x8*)(cB + (size_t)un * 8);
    }
    if (kt + 1 < 32) stage(As[cur ^ 1], Bs[cur ^ 1], kt + 1);
#pragma unroll
    for (int i = 0; i < 4; i++)
#pragma unroll
      for (int j = 0; j < 4; j++) acc[i][j] = mfma16(af[i], bfr[j], acc[i][j]);
    cur ^= 1;
  }
}

// ---------------- QKV projection + RoPE epilogue ----------------
// out layouts: q/k/v [32 bh][2048 t][64 d] bf16; q pre-scaled by 1/8
__global__ __launch_bounds__(256) void gemm_qkv(
    const bf16* __restrict__ xb, const bf16* __restrict__ wq,
    const bf16* __restrict__ wk, const bf16* __restrict__ wv,
    const float* __restrict__ ct, const float* __restrict__ st,
    bf16* __restrict__ qo, bf16* __restrict__ ko, bf16* __restrict__ vo) {
  __shared__ __align__(16) bf16 As[2][4096];
  __shared__ __align__(16) bf16 Bs[2][4096];
  int bm = blockIdx.x, bn = blockIdx.y;
  int proj = bn >> 3;
  const bf16* W = proj == 0 ? wq : (proj == 1 ? wk : wv);
  bf16* out = proj == 0 ? qo : (proj == 1 ? ko : vo);
  int m0 = bm * 128, n0 = (bn & 7) * 128;

  f32x4 zero = {0.f, 0.f, 0.f, 0.f};
  f32x4 acc[4][4];
#pragma unroll
  for (int i = 0; i < 4; i++)
#pragma unroll
    for (int j = 0; j < 4; j++) acc[i][j] = zero;

  gemm_mainloop(xb, W, m0, n0, As, Bs, acc);

  const int tid = threadIdx.x, lane = tid & 63, wave = tid >> 6;
  const int wr = (wave >> 1) * 64, wc = (wave & 1) * 64;
  const int lr = lane & 15, lh = lane >> 4;
  int colb = n0 + wc;          // multiple of 64 -> single head per wave window
  int h = colb >> 6;
#pragma unroll
  for (int i = 0; i < 4; i++) {
#pragma unroll
    for (int r = 0; r < 4; r++) {
      int m = m0 + wr + i * 16 + lh * 4 + r;
      int b = m >> 11, t = m & 2047;
      float v0 = acc[i][0][r], v1 = acc[i][1][r];
      float v2 = acc[i][2][r], v3 = acc[i][3][r];
      if (proj < 2) {  // RoPE: pairs (d, d+32) are frags (0,2) and (1,3)
        float c0 = ct[t * 32 + lr],      s0 = st[t * 32 + lr];
        float c1 = ct[t * 32 + 16 + lr], s1 = st[t * 32 + 16 + lr];
        float n0v = v0 * c0 - v2 * s0, n2 = v2 * c0 + v0 * s0;
        float n1 = v1 * c1 - v3 * s1,  n3 = v3 * c1 + v1 * s1;
        v0 = n0v; v1 = n1; v2 = n2; v3 = n3;
        if (proj == 0) { v0 *= 0.125f; v1 *= 0.125f; v2 *= 0.125f; v3 *= 0.125f; }
      }
      size_t base = ((size_t)(b * 16 + h) * 2048 + t) * 64;
      out[base + lr]      = (bf16)v0;
      out[base + 16 + lr] = (bf16)v1;
      out[base + 32 + lr] = (bf16)v2;
      out[base + 48 + lr] = (bf16)v3;
    }
  }
}

// ---------------- V transpose: [bh][t][d] -> [bh][d][t] ----------------
__global__ __launch_bounds__(256) void vtrans(const bf16* __restrict__ v,
                                              bf16* __restrict__ vt) {
  __shared__ bf16 tile[64][68];
  int bh = blockIdx.x, tt = blockIdx.y;
  int tid = threadIdx.x;
  const bf16* src = v + ((size_t)bh * 2048 + tt * 64) * 64;
  int rr0 = tid >> 4;
  int c4 = (tid & 15) * 4;
#pragma unroll
  for (int p = 0; p < 4; p++) {
    int r = p * 16 + rr0;
    *(uint2*)&tile[r][c4] = *(const uint2*)(src + (size_t)r * 64 + c4);
  }
  __syncthreads();
  bf16* dst = vt + (size_t)bh * 64 * 2048 + tt * 64;
#pragma unroll
  for (int p = 0; p < 4; p++) {
    int d = p * 16 + rr0;
    union { bf16 h[4]; uint2 u; } o;
#pragma unroll
    for (int q = 0; q < 4; q++) o.h[q] = tile[c4 + q][d];
    *(uint2*)(dst + (size_t)d * 2048 + c4) = o.u;
  }
}

// ---------------- flash attention ----------------
// 4 waves x 64 q-rows (Q-tile 256), KV tile 128 double-buffered.
// Q pre-scaled by 1/8. out: [b][t][h*64+d] bf16 (row-major [4096][1024]).
__global__ __launch_bounds__(256) void attn(const bf16* __restrict__ q,
                                            const bf16* __restrict__ k,
                                            const bf16* __restrict__ vt,
                                            bf16* __restrict__ o) {
  __shared__ __align__(16) bf16 kbuf[2][8192];
  __shared__ __align__(16) bf16 vbuf[2][8192];
  __shared__ __align__(16) bf16 pbuf[4][2048];
  // XCD swizzle: all 8 q-tiles of a bh land on one XCD (id%8 assumed rr)
  int id = blockIdx.x;
  int xc = id & 7, jj = id >> 3;
  int bh = xc * 4 + (jj >> 3), qt = jj & 7;

  const int tid = threadIdx.x, lane = tid & 63, wave = tid >> 6;
  const int lr = lane & 15, lh = lane >> 4;

  // Q fragments (held in regs; rows wave*64 + i*16 + lr)
  bf16x8 aq[4][2];
  const bf16* qb = q + ((size_t)bh * 2048 + qt * 256 + wave * 64) * 64;
#pragma unroll
  for (int i = 0; i < 4; i++)
#pragma unroll
    for (int kk = 0; kk < 2; kk++)
      aq[i][kk] = *(const bf16x8*)(qb + (size_t)(i * 16 + lr) * 64 + kk * 32 + lh * 8);

  f32x4 zero = {0.f, 0.f, 0.f, 0.f};
  f32x4 acc[4][4];
#pragma unroll
  for (int i = 0; i < 4; i++)
#pragma unroll
    for (int jd = 0; jd < 4; jd++) acc[i][jd] = zero;
  float mrow[16], lrow[16];
#pragma unroll
  for (int i = 0; i < 16; i++) { mrow[i] = -1e30f; lrow[i] = 0.f; }

  const bf16* kg = k + (size_t)bh * 2048 * 64;
  const bf16* vg = vt + (size_t)bh * 64 * 2048;
  auto stageK = [&](bf16* dst, int kv0) {
#pragma unroll
    for (int p = 0; p < 4; p++) {
      int u = p * 256 + tid; int row = u >> 3; int sg = (u & 7) ^ (row & 7);
      gload16(dst + (size_t)u * 8, kg + (size_t)(kv0 + row) * 64 + sg * 8);
    }
  };
  auto stageV = [&](bf16* dst, int kv0) {
#pragma unroll
    for (int p = 0; p < 4; p++) {
      int u = p * 256 + tid; int row = u >> 4; int sg = (u & 15) ^ (row & 7);
      gload16(dst + (size_t)u * 8, vg + (size_t)row * 2048 + kv0 + sg * 8);
    }
  };

  stageK(kbuf[0], 0);
  stageV(vbuf[0], 0);
  bf16* pw = pbuf[wave];
  int cur = 0;

  for (int it = 0; it < 16; ++it) {
    __syncthreads();
    const bf16* kb = kbuf[cur]; const bf16* vb = vbuf[cur];
    // K fragments: B-op of S = Q K^T (swizzled reads)
    bf16x8 bk[8][2];
#pragma unroll
    for (int j = 0; j < 8; j++) {
      int row = j * 16 + lr;
#pragma unroll
      for (int kk = 0; kk < 2; kk++) {
        int un = row * 8 + ((kk * 4 + lh) ^ (row & 7));
        bk[j][kk] = *(const bf16x8*)(kb + (size_t)un * 8);
      }
    }
    // V^T fragments: B-op of O += P V
    bf16x8 vf[4][4];
#pragma unroll
    for (int jd = 0; jd < 4; jd++) {
      int row = jd * 16 + lr;
#pragma unroll
      for (int kb4 = 0; kb4 < 4; kb4++) {
        int un = row * 16 + ((kb4 * 4 + lh) ^ (row & 7));
        vf[jd][kb4] = *(const bf16x8*)(vb + (size_t)un * 8);
      }
    }
    if (it + 1 < 16) { stageK(kbuf[cur ^ 1], (it + 1) * 128); stageV(vbuf[cur ^ 1], (it + 1) * 128); }

#pragma unroll
    for (int i = 0; i < 4; i++) {
      f32x4 sv[8];
#pragma unroll
      for (int j = 0; j < 8; j++) {
        f32x4 z = zero;
        z = mfma16(aq[i][0], bk[j][0], z);
        z = mfma16(aq[i][1], bk[j][1], z);
        sv[j] = z;  // already scaled (q pre-scaled by 1/8)
      }
#pragma unroll
      for (int r = 0; r < 4; r++) {
        float m1 = sv[0][r];
#pragma unroll
        for (int j = 1; j < 8; j++) m1 = fmaxf(m1, sv[j][r]);
        m1 = fmaxf(m1, __shfl_xor(m1, 1));
        m1 = fmaxf(m1, __shfl_xor(m1, 2));
        m1 = fmaxf(m1, __shfl_xor(m1, 4));
        m1 = fmaxf(m1, __shfl_xor(m1, 8));
        int ridx = i * 4 + r;
        float mo = mrow[ridx];
        float mn = fmaxf(mo, m1);
        float fsc = exp2f((mo - mn) * L2E);
        acc[i][0][r] *= fsc; acc[i][1][r] *= fsc;
        acc[i][2][r] *= fsc; acc[i][3][r] *= fsc;
        float su = 0.f;
        int rr = lh * 4 + r;
#pragma unroll
        for (int j = 0; j < 8; j++) {
          float p = exp2f((sv[j][r] - mn) * L2E);
          su += p;
          int col = j * 16 + lr;
          int un = rr * 16 + ((col >> 3) ^ (rr & 7));
          pw[un * 8 + (col & 7)] = (bf16)p;  // per-wave private buffer
        }
        su += __shfl_xor(su, 1); su += __shfl_xor(su, 2);
        su += __shfl_xor(su, 4); su += __shfl_xor(su, 8);
        lrow[ridx] = lrow[ridx] * fsc + su;
        mrow[ridx] = mn;
      }
      // PV: A-op = P from pbuf (swizzled), accumulate into acc[i][*]
#pragma unroll
      for (int kb4 = 0; kb4 < 4; kb4++) {
        int un = lr * 16 + ((kb4 * 4 + lh) ^ (lr & 7));
        bf16x8 pa = *(const bf16x8*)(pw + (size_t)un * 8);
#pragma unroll
        for (int jd = 0; jd < 4; jd++)
          acc[i][jd] = mfma16(pa, vf[jd][kb4], acc[i][jd]);
      }
    }
    cur ^= 1;
  }

  int b = bh >> 4, h = bh & 15;
#pragma unroll
  for (int i = 0; i < 4; i++)
#pragma unroll
    for (int r = 0; r < 4; r++) {
      float inv = 1.0f / lrow[i * 4 + r];
      int qrow = qt * 256 + wave * 64 + i * 16 + lh * 4 + r;
      size_t base = ((size_t)(b * 2048 + qrow)) * 1024 + h * 64;
#pragma unroll
      for (int jd = 0; jd < 4; jd++)
        o[base + jd * 16 + lr] = (bf16)(acc[i][jd][r] * inv);
    }
}

// ---------------- output projection: fp32 epilogue into d_out ----------------
__global__ __launch_bounds__(256) void gemm_out(const bf16* __restrict__ ab,
                                                const bf16* __restrict__ wo,
                                                float* __restrict__ out) {
  __shared__ __align__(16) bf16 As[2][4096];
  __shared__ __align__(16) bf16 Bs[2][4096];
  int m0 = blockIdx.x * 128, n0 = blockIdx.y * 128;
  f32x4 zero = {0.f, 0.f, 0.f, 0.f};
  f32x4 acc[4][4];
#pragma unroll
  for (int i = 0; i < 4; i++)
#pragma unroll
    for (int j = 0; j < 4; j++) acc[i][j] = zero;

  gemm_mainloop(ab, wo, m0, n0, As, Bs, acc);

  const int tid = threadIdx.x, lane = tid & 63, wave = tid >> 6;
  const int wr = (wave >> 1) * 64, wc = (wave & 1) * 64;
  const int lr = lane & 15, lh = lane >> 4;
#pragma unroll
  for (int i = 0; i < 4; i++)
#pragma unroll
    for (int r = 0; r < 4; r++) {
      int m = m0 + wr + i * 16 + lh * 4 + r;
#pragma unroll
      for (int j = 0; j < 4; j++) {
        int col = n0 + wc + j * 16 + lr;
        out[(size_t)m * 1024 + col] = acc[i][j][r];
      }
    }
}

extern "C" void kernel_launch(void* const* d_in, const int* in_sizes, int n_in,
                              void* d_out, int out_size, void* d_ws, size_t ws_size,
                              hipStream_t stream) {
  const float* x  = (const float*)d_in[0];
  const float* wq = (const float*)d_in[1];
  const float* wk = (const float*)d_in[2];
  const float* wv = (const float*)d_in[3];
  const float* wo = (const float*)d_in[4];
  float* out = (float*)d_out;
  char* ws = (char*)d_ws;
  const size_t MB = 1u << 20;
  bf16* xb  = (bf16*)(ws + 0);
  bf16* wqb = (bf16*)(ws + 8 * MB);
  bf16* wkb = (bf16*)(ws + 10 * MB);
  bf16* wvb = (bf16*)(ws + 12 * MB);
  bf16* wob = (bf16*)(ws + 14 * MB);
  bf16* qw  = (bf16*)(ws + 16 * MB);
  bf16* kw  = (bf16*)(ws + 24 * MB);
  bf16* vw  = (bf16*)(ws + 32 * MB);
  bf16* vtw = (bf16*)(ws + 40 * MB);
  bf16* aw  = (bf16*)(ws + 48 * MB);
  float* ct = (float*)(ws + 56 * MB);
  float* st = (float*)(ws + 56 * MB + 256 * 1024);

  prep_cast<<<8192, 256, 0, stream>>>(x, wq, wk, wv, wo, xb, wqb, wkb, wvb, wob);
  rope_tab<<<256, 256, 0, stream>>>(ct, st);
  gemm_qkv<<<dim3(32, 24), 256, 0, stream>>>(xb, wqb, wkb, wvb, ct, st, qw, kw, vw);
  vtrans<<<dim3(32, 32), 256, 0, stream>>>(vw, vtw);
  attn<<<256, 256, 0, stream>>>(qw, kw, vtw, aw);
  gemm_out<<<dim3(32, 8), 256, 0, stream>>>(aw, wob, out);
}